// Round 1
// baseline (482.147 us; speedup 1.0000x reference)
//
#include <hip/hip_runtime.h>
#include <hip/hip_bf16.h>
#include <cstdint>
#include <cstddef>

#define N_NODES 262144
#define NGRAPH  2048
#define DIM     512
#define HID3    1536
#define OUTD    128

typedef __attribute__((ext_vector_type(8))) short  short8;
typedef __attribute__((ext_vector_type(4))) float  floatx4;

__device__ inline unsigned short f2bf(float f) {
    union { float f; uint32_t u; } v; v.f = f;
    uint32_t u = v.u;
    return (unsigned short)((u + 0x7fffu + ((u >> 16) & 1u)) >> 16);
}
__device__ inline float bf2f(unsigned short h) {
    union { uint32_t u; float f; } v; v.u = ((uint32_t)h) << 16; return v.f;
}

// ---------------- graph boundaries (segment_ids sorted) ----------------
__global__ void k_starts(const int* __restrict__ seg, int* __restrict__ starts) {
    int b = blockIdx.x * blockDim.x + threadIdx.x;
    if (b > NGRAPH) return;
    int lo = 0, hi = N_NODES;
    while (lo < hi) { int mid = (lo + hi) >> 1; if (seg[mid] < b) lo = mid + 1; else hi = mid; }
    starts[b] = lo;
}

// ---------------- fp32 -> bf16 weight convert ----------------
__global__ void k_cvt(const float* __restrict__ in, unsigned short* __restrict__ out, int n) {
    int i = blockIdx.x * blockDim.x + threadIdx.x;
    if (i < n) out[i] = f2bf(in[i]);
}

// transpose-convert W_node [512(k) x 512(f)] -> WnT [512(f) x 512(k)] bf16
__global__ void k_cvtT(const float* __restrict__ W, unsigned short* __restrict__ Wt) {
    __shared__ float tile[32][33];
    int bx = blockIdx.x, by = blockIdx.y;
    int tx = threadIdx.x, ty = threadIdx.y; // 32 x 8
    for (int r = 0; r < 32; r += 8)
        tile[ty + r][tx] = W[(size_t)(bx * 32 + ty + r) * DIM + by * 32 + tx];
    __syncthreads();
    for (int r = 0; r < 32; r += 8)
        Wt[(size_t)(by * 32 + ty + r) * DIM + bx * 32 + tx] = f2bf(tile[tx][ty + r]);
}

// ---------------- init: sum-pool h0, left_att, optional x->bf16 ----------------
template<bool WRITE_XBF>
__global__ __launch_bounds__(256) void k_init(const float* __restrict__ x,
        const int* __restrict__ starts, const float* __restrict__ watl,
        float* __restrict__ left_att, float* __restrict__ hcur,
        unsigned short* __restrict__ hcur_bf, unsigned short* __restrict__ xbf) {
    __shared__ float wl[DIM];
    __shared__ float red[4 * DIM];
    int b = blockIdx.x, t = threadIdx.x;
    wl[t] = watl[t]; wl[t + 256] = watl[t + 256];
    __syncthreads();
    int s = starts[b], e = starts[b + 1];
    int w = t >> 6, lane = t & 63;
    int f0 = lane * 4;
    float acc[8] = {0.f,0.f,0.f,0.f,0.f,0.f,0.f,0.f};
    for (int i = s + w; i < e; i += 4) {
        float4 v0 = *reinterpret_cast<const float4*>(x + (size_t)i * DIM + f0);
        float4 v1 = *reinterpret_cast<const float4*>(x + (size_t)i * DIM + 256 + f0);
        acc[0] += v0.x; acc[1] += v0.y; acc[2] += v0.z; acc[3] += v0.w;
        acc[4] += v1.x; acc[5] += v1.y; acc[6] += v1.z; acc[7] += v1.w;
        float dot = v0.x*wl[f0] + v0.y*wl[f0+1] + v0.z*wl[f0+2] + v0.w*wl[f0+3]
                  + v1.x*wl[256+f0] + v1.y*wl[256+f0+1] + v1.z*wl[256+f0+2] + v1.w*wl[256+f0+3];
        #pragma unroll
        for (int off = 32; off > 0; off >>= 1) dot += __shfl_xor(dot, off);
        if (lane == 0) left_att[i] = dot;
        if constexpr (WRITE_XBF) {
            ushort4 o0, o1;
            o0.x = f2bf(v0.x); o0.y = f2bf(v0.y); o0.z = f2bf(v0.z); o0.w = f2bf(v0.w);
            o1.x = f2bf(v1.x); o1.y = f2bf(v1.y); o1.z = f2bf(v1.z); o1.w = f2bf(v1.w);
            *reinterpret_cast<ushort4*>(xbf + (size_t)i * DIM + f0) = o0;
            *reinterpret_cast<ushort4*>(xbf + (size_t)i * DIM + 256 + f0) = o1;
        }
    }
    #pragma unroll
    for (int j = 0; j < 4; j++) {
        red[w * DIM + f0 + j]       = acc[j];
        red[w * DIM + 256 + f0 + j] = acc[4 + j];
    }
    __syncthreads();
    float s0 = red[t]       + red[DIM + t]       + red[2*DIM + t]       + red[3*DIM + t];
    float s1 = red[256 + t] + red[DIM + 256 + t] + red[2*DIM + 256 + t] + red[3*DIM + 256 + t];
    hcur[(size_t)b * DIM + t] = s0;
    hcur[(size_t)b * DIM + 256 + t] = s1;
    hcur_bf[(size_t)b * DIM + t] = f2bf(s0);
    hcur_bf[(size_t)b * DIM + 256 + t] = f2bf(s1);
}

// ---------------- per-timestep: right_att dot + segment softmax ----------------
__global__ __launch_bounds__(256) void k_soft(const float* __restrict__ hcur,
        const float* __restrict__ watr, const float* __restrict__ left_att,
        const int* __restrict__ starts, float* __restrict__ ebuf, float* __restrict__ invden) {
    __shared__ float red[256];
    int b = blockIdx.x, t = threadIdx.x;
    float p = hcur[(size_t)b * DIM + t] * watr[t] + hcur[(size_t)b * DIM + 256 + t] * watr[256 + t];
    red[t] = p; __syncthreads();
    for (int off = 128; off > 0; off >>= 1) { if (t < off) red[t] += red[t + off]; __syncthreads(); }
    float ra = red[0];
    __syncthreads();
    int s = starts[b], e = starts[b + 1];
    float m = -1e30f;
    for (int i = s + t; i < e; i += 256) {
        float a = left_att[i] + ra; a = a >= 0.f ? a : 0.01f * a;
        m = fmaxf(m, a);
    }
    red[t] = m; __syncthreads();
    for (int off = 128; off > 0; off >>= 1) { if (t < off) red[t] = fmaxf(red[t], red[t + off]); __syncthreads(); }
    m = red[0];
    __syncthreads();
    float sum = 0.f;
    for (int i = s + t; i < e; i += 256) {
        float a = left_att[i] + ra; a = a >= 0.f ? a : 0.01f * a;
        float ev = expf(a - m);
        ebuf[i] = ev; sum += ev;
    }
    red[t] = sum; __syncthreads();
    for (int off = 128; off > 0; off >>= 1) { if (t < off) red[t] += red[t + off]; __syncthreads(); }
    if (t == 0) { float d = red[0]; invden[b] = d > 0.f ? 1.0f / d : 0.0f; }
}

// ---------------- weighted segment sum of x -> sw_bf ----------------
template<bool XBF>
__global__ __launch_bounds__(256) void k_wsum(const float* __restrict__ x,
        const unsigned short* __restrict__ xbf, const float* __restrict__ ebuf,
        const int* __restrict__ starts, const float* __restrict__ invden,
        unsigned short* __restrict__ sw_bf) {
    __shared__ float red[4 * DIM];
    int b = blockIdx.x, t = threadIdx.x;
    int w = t >> 6, lane = t & 63;
    int s = starts[b], e = starts[b + 1];
    float acc[8] = {0.f,0.f,0.f,0.f,0.f,0.f,0.f,0.f};
    if constexpr (XBF) {
        int f0 = lane * 8;
        for (int i = s + w; i < e; i += 4) {
            float ev = ebuf[i];
            short8 v = *reinterpret_cast<const short8*>(xbf + (size_t)i * DIM + f0);
            #pragma unroll
            for (int j = 0; j < 8; j++) acc[j] += ev * bf2f((unsigned short)v[j]);
        }
        #pragma unroll
        for (int j = 0; j < 8; j++) red[w * DIM + f0 + j] = acc[j];
    } else {
        int f0 = lane * 4;
        for (int i = s + w; i < e; i += 4) {
            float ev = ebuf[i];
            float4 v0 = *reinterpret_cast<const float4*>(x + (size_t)i * DIM + f0);
            float4 v1 = *reinterpret_cast<const float4*>(x + (size_t)i * DIM + 256 + f0);
            acc[0] += ev * v0.x; acc[1] += ev * v0.y; acc[2] += ev * v0.z; acc[3] += ev * v0.w;
            acc[4] += ev * v1.x; acc[5] += ev * v1.y; acc[6] += ev * v1.z; acc[7] += ev * v1.w;
        }
        #pragma unroll
        for (int j = 0; j < 4; j++) {
            red[w * DIM + f0 + j]       = acc[j];
            red[w * DIM + 256 + f0 + j] = acc[4 + j];
        }
    }
    __syncthreads();
    float inv = invden[b];
    float s0 = (red[t]       + red[DIM + t]       + red[2*DIM + t]       + red[3*DIM + t])       * inv;
    float s1 = (red[256 + t] + red[DIM + 256 + t] + red[2*DIM + 256 + t] + red[3*DIM + 256 + t]) * inv;
    sw_bf[(size_t)b * DIM + t] = f2bf(s0);
    sw_bf[(size_t)b * DIM + 256 + t] = f2bf(s1);
}

// ---------------- bf16 MFMA GEMM: C[M x Ncols] = A[M x 512] @ Wt[Ncols x 512]^T ----------------
// M = 2048 fixed. Tile 128x128, 4 waves (2x2), each wave 64x64 = 4x4 frags of 16x16x32.
template<bool ELU_BF>
__global__ __launch_bounds__(256) void k_gemm(const unsigned short* __restrict__ A,
        const unsigned short* __restrict__ Wt, float* __restrict__ Cf,
        unsigned short* __restrict__ Cbf, int Ncols) {
    __shared__ unsigned short lA[128 * 40];
    __shared__ unsigned short lW[128 * 40];
    int t = threadIdx.x;
    int w = t >> 6, lane = t & 63;
    int wr = w >> 1, wc = w & 1;
    int mbase = blockIdx.x * 128;
    int nbase = blockIdx.y * 128;

    floatx4 acc[4][4];
    #pragma unroll
    for (int m = 0; m < 4; m++)
        #pragma unroll
        for (int n = 0; n < 4; n++) {
            acc[m][n][0] = 0.f; acc[m][n][1] = 0.f; acc[m][n][2] = 0.f; acc[m][n][3] = 0.f;
        }

    int srow = t >> 1;
    int scol = (t & 1) * 16;
    const unsigned short* gA = A  + (size_t)(mbase + srow) * DIM + scol;
    const unsigned short* gW = Wt + (size_t)(nbase + srow) * DIM + scol;
    unsigned short* sA = lA + srow * 40 + scol;
    unsigned short* sW = lW + srow * 40 + scol;

    int fr = lane & 15, kg = (lane >> 4) * 8;

    for (int kk = 0; kk < DIM; kk += 32) {
        short8 a0 = *reinterpret_cast<const short8*>(gA + kk);
        short8 a1 = *reinterpret_cast<const short8*>(gA + kk + 8);
        short8 w0 = *reinterpret_cast<const short8*>(gW + kk);
        short8 w1 = *reinterpret_cast<const short8*>(gW + kk + 8);
        __syncthreads();
        *reinterpret_cast<short8*>(sA)     = a0;
        *reinterpret_cast<short8*>(sA + 8) = a1;
        *reinterpret_cast<short8*>(sW)     = w0;
        *reinterpret_cast<short8*>(sW + 8) = w1;
        __syncthreads();
        short8 af[4], bfr[4];
        #pragma unroll
        for (int m = 0; m < 4; m++)
            af[m] = *reinterpret_cast<const short8*>(lA + (wr*64 + m*16 + fr) * 40 + kg);
        #pragma unroll
        for (int n = 0; n < 4; n++)
            bfr[n] = *reinterpret_cast<const short8*>(lW + (wc*64 + n*16 + fr) * 40 + kg);
        #pragma unroll
        for (int m = 0; m < 4; m++)
            #pragma unroll
            for (int n = 0; n < 4; n++)
                acc[m][n] = __builtin_amdgcn_mfma_f32_16x16x32_bf16(af[m], bfr[n], acc[m][n], 0, 0, 0);
    }

    int rq = (lane >> 4) * 4;
    #pragma unroll
    for (int m = 0; m < 4; m++) {
        #pragma unroll
        for (int n = 0; n < 4; n++) {
            int col = nbase + wc*64 + n*16 + fr;
            #pragma unroll
            for (int r = 0; r < 4; r++) {
                int row = mbase + wr*64 + m*16 + rq + r;
                float v = acc[m][n][r];
                if constexpr (ELU_BF) {
                    v = v > 0.f ? v : (expf(v) - 1.0f);
                    Cbf[(size_t)row * Ncols + col] = f2bf(v);
                } else {
                    Cf[(size_t)row * Ncols + col] = v;
                }
            }
        }
    }
}

// ---------------- GRU gates + silu (pointwise) ----------------
__global__ __launch_bounds__(256) void k_gate(const float* __restrict__ gi,
        const float* __restrict__ gh, const float* __restrict__ bih,
        const float* __restrict__ bhh, float* __restrict__ hcur,
        unsigned short* __restrict__ hcur_bf) {
    int idx = blockIdx.x * 256 + threadIdx.x;   // over NGRAPH*512
    int b = idx >> 9, j = idx & 511;
    size_t gb = (size_t)b * HID3;
    float gir = gi[gb + j]        + bih[j];
    float giz = gi[gb + 512 + j]  + bih[512 + j];
    float gin = gi[gb + 1024 + j] + bih[1024 + j];
    float ghr = gh[gb + j]        + bhh[j];
    float ghz = gh[gb + 512 + j]  + bhh[512 + j];
    float ghn = gh[gb + 1024 + j] + bhh[1024 + j];
    float r = 1.0f / (1.0f + expf(-(gir + ghr)));
    float z = 1.0f / (1.0f + expf(-(giz + ghz)));
    float n = tanhf(gin + r * ghn);
    float h = hcur[(size_t)b * DIM + j];
    float nh = (1.0f - z) * n + z * h;
    float out = nh / (1.0f + expf(-nh));     // silu
    hcur[(size_t)b * DIM + j] = out;
    hcur_bf[(size_t)b * DIM + j] = f2bf(out);
}

// ---------------- final linear: out = hcur @ W_lin + b_lin ----------------
__global__ __launch_bounds__(128) void k_fin(const float* __restrict__ hcur,
        const float* __restrict__ Wlin, const float* __restrict__ blin,
        float* __restrict__ out) {
    __shared__ float rows[16 * DIM];
    int t = threadIdx.x;
    int b0 = blockIdx.x * 16;
    for (int i = t; i < 16 * DIM / 4; i += 128)
        reinterpret_cast<float4*>(rows)[i] = reinterpret_cast<const float4*>(hcur + (size_t)b0 * DIM)[i];
    __syncthreads();
    float acc[16];
    #pragma unroll
    for (int r = 0; r < 16; r++) acc[r] = 0.f;
    #pragma unroll 4
    for (int k = 0; k < DIM; k++) {
        float wv = Wlin[k * OUTD + t];
        #pragma unroll
        for (int r = 0; r < 16; r++) acc[r] += rows[r * DIM + k] * wv;
    }
    float bl = blin[t];
    #pragma unroll
    for (int r = 0; r < 16; r++) out[(size_t)(b0 + r) * OUTD + t] = acc[r] + bl;
}

extern "C" void kernel_launch(void* const* d_in, const int* in_sizes, int n_in,
                              void* d_out, int out_size, void* d_ws, size_t ws_size,
                              hipStream_t stream) {
    const float* x     = (const float*)d_in[0];
    const int*   seg   = (const int*)d_in[1];
    const float* watl  = (const float*)d_in[2];
    const float* watr  = (const float*)d_in[3];
    const float* Wnode = (const float*)d_in[4];
    const float* Wih   = (const float*)d_in[5];
    const float* Whh   = (const float*)d_in[6];
    const float* bih   = (const float*)d_in[7];
    const float* bhh   = (const float*)d_in[8];
    const float* Wlin  = (const float*)d_in[9];
    const float* blin  = (const float*)d_in[10];
    float* out = (float*)d_out;

    char* ws = (char*)d_ws;
    size_t off = 0;
    auto alloc = [&](size_t bytes) -> void* {
        void* p = ws + off;
        off += bytes;
        off = (off + 255) & ~(size_t)255;
        return p;
    };
    int*            starts  = (int*)            alloc((NGRAPH + 1) * sizeof(int));
    float*          left    = (float*)          alloc((size_t)N_NODES * sizeof(float));
    float*          ebuf    = (float*)          alloc((size_t)N_NODES * sizeof(float));
    float*          hcur    = (float*)          alloc((size_t)NGRAPH * DIM * sizeof(float));
    unsigned short* hcurbf  = (unsigned short*) alloc((size_t)NGRAPH * DIM * 2);
    unsigned short* hgbf    = (unsigned short*) alloc((size_t)NGRAPH * DIM * 2);
    unsigned short* swbf    = (unsigned short*) alloc((size_t)NGRAPH * DIM * 2);
    float*          gi      = (float*)          alloc((size_t)NGRAPH * HID3 * sizeof(float));
    float*          gh      = (float*)          alloc((size_t)NGRAPH * HID3 * sizeof(float));
    unsigned short* WnT     = (unsigned short*) alloc((size_t)DIM * DIM * 2);
    unsigned short* Wihb    = (unsigned short*) alloc((size_t)HID3 * DIM * 2);
    unsigned short* Whhb    = (unsigned short*) alloc((size_t)HID3 * DIM * 2);
    float*          invd    = (float*)          alloc((size_t)NGRAPH * sizeof(float));
    unsigned short* xbf     = (unsigned short*)(ws + off);
    bool use_xbf = (off + (size_t)N_NODES * DIM * 2) <= ws_size;

    k_starts<<<(NGRAPH + 256) / 256, 256, 0, stream>>>(seg, starts);
    k_cvt<<<(HID3 * DIM) / 256, 256, 0, stream>>>(Wih, Wihb, HID3 * DIM);
    k_cvt<<<(HID3 * DIM) / 256, 256, 0, stream>>>(Whh, Whhb, HID3 * DIM);
    k_cvtT<<<dim3(16, 16), dim3(32, 8), 0, stream>>>(Wnode, WnT);

    if (use_xbf)
        k_init<true ><<<NGRAPH, 256, 0, stream>>>(x, starts, watl, left, hcur, hcurbf, xbf);
    else
        k_init<false><<<NGRAPH, 256, 0, stream>>>(x, starts, watl, left, hcur, hcurbf, nullptr);

    for (int ts = 0; ts < 2; ts++) {
        k_soft<<<NGRAPH, 256, 0, stream>>>(hcur, watr, left, starts, ebuf, invd);
        if (use_xbf)
            k_wsum<true ><<<NGRAPH, 256, 0, stream>>>(x, xbf, ebuf, starts, invd, swbf);
        else
            k_wsum<false><<<NGRAPH, 256, 0, stream>>>(x, xbf, ebuf, starts, invd, swbf);
        // gat = elu(sw @ W_node) -> hgbf (bf16)
        k_gemm<true ><<<dim3(NGRAPH / 128, DIM / 128), 256, 0, stream>>>(swbf, WnT, nullptr, hgbf, DIM);
        // gi = hg @ W_ih^T ; gh = hcur @ W_hh^T
        k_gemm<false><<<dim3(NGRAPH / 128, HID3 / 128), 256, 0, stream>>>(hgbf,   Wihb, gi, nullptr, HID3);
        k_gemm<false><<<dim3(NGRAPH / 128, HID3 / 128), 256, 0, stream>>>(hcurbf, Whhb, gh, nullptr, HID3);
        k_gate<<<(NGRAPH * DIM) / 256, 256, 0, stream>>>(gi, gh, bih, bhh, hcur, hcurbf);
    }
    k_fin<<<NGRAPH / 16, 128, 0, stream>>>(hcur, Wlin, blin, out);
}

// Round 2
// 432.122 us; speedup vs baseline: 1.1158x; 1.1158x over previous
//
#include <hip/hip_runtime.h>
#include <hip/hip_bf16.h>
#include <cstdint>
#include <cstddef>

#define N_NODES 262144
#define NGRAPH  2048
#define DIM     512
#define HID3    1536
#define OUTD    128

typedef __attribute__((ext_vector_type(8))) short  short8;
typedef __attribute__((ext_vector_type(4))) float  floatx4;

__device__ inline unsigned short f2bf(float f) {
    union { float f; uint32_t u; } v; v.f = f;
    uint32_t u = v.u;
    return (unsigned short)((u + 0x7fffu + ((u >> 16) & 1u)) >> 16);
}
__device__ inline float bf2f(unsigned short h) {
    union { uint32_t u; float f; } v; v.u = ((uint32_t)h) << 16; return v.f;
}

__device__ __forceinline__ void gload_lds16(const void* g, void* l) {
    __builtin_amdgcn_global_load_lds((const __attribute__((address_space(1))) void*)g,
                                     (__attribute__((address_space(3))) void*)l, 16, 0, 0);
}

// ---------------- prep: weight converts + transpose + graph starts ----------------
__global__ __launch_bounds__(256) void k_prep(const float* __restrict__ Wih,
        const float* __restrict__ Whh, const float* __restrict__ Wnode,
        const int* __restrict__ seg, unsigned short* __restrict__ Wihb,
        unsigned short* __restrict__ Whhb, unsigned short* __restrict__ WnT,
        int* __restrict__ starts) {
    __shared__ float tile[32][33];
    int id = blockIdx.x, t = threadIdx.x;
    if (id < 3072) {
        int i = id * 256 + t; Wihb[i] = f2bf(Wih[i]);
    } else if (id < 6144) {
        int i = (id - 3072) * 256 + t; Whhb[i] = f2bf(Whh[i]);
    } else if (id < 6400) {
        int idx = id - 6144;
        int bx = idx >> 4, by = idx & 15;
        int tx = t & 31, ty = t >> 5;
        for (int r = 0; r < 32; r += 8)
            tile[ty + r][tx] = Wnode[(size_t)(bx * 32 + ty + r) * DIM + by * 32 + tx];
        __syncthreads();
        for (int r = 0; r < 32; r += 8)
            WnT[(size_t)(by * 32 + ty + r) * DIM + bx * 32 + tx] = f2bf(tile[tx][ty + r]);
    } else {
        int b = (id - 6400) * 256 + t;
        if (b <= NGRAPH) {
            int lo = 0, hi = N_NODES;
            while (lo < hi) { int mid = (lo + hi) >> 1; if (seg[mid] < b) lo = mid + 1; else hi = mid; }
            starts[b] = lo;
        }
    }
}

// ---------------- init: sum-pool h0, left_att, x->bf16 ----------------
template<bool WRITE_XBF>
__global__ __launch_bounds__(256) void k_init(const float* __restrict__ x,
        const int* __restrict__ starts, const float* __restrict__ watl,
        float* __restrict__ left_att, float* __restrict__ hcur,
        unsigned short* __restrict__ hcur_bf, unsigned short* __restrict__ xbf) {
    __shared__ float wl[DIM];
    __shared__ float red[4 * DIM];
    int b = blockIdx.x, t = threadIdx.x;
    wl[t] = watl[t]; wl[t + 256] = watl[t + 256];
    __syncthreads();
    int s = starts[b], e = starts[b + 1];
    int w = t >> 6, lane = t & 63;
    int f0 = lane * 4;
    float acc[8] = {0.f,0.f,0.f,0.f,0.f,0.f,0.f,0.f};
    for (int i = s + w; i < e; i += 4) {
        float4 v0 = *reinterpret_cast<const float4*>(x + (size_t)i * DIM + f0);
        float4 v1 = *reinterpret_cast<const float4*>(x + (size_t)i * DIM + 256 + f0);
        acc[0] += v0.x; acc[1] += v0.y; acc[2] += v0.z; acc[3] += v0.w;
        acc[4] += v1.x; acc[5] += v1.y; acc[6] += v1.z; acc[7] += v1.w;
        float dot = v0.x*wl[f0] + v0.y*wl[f0+1] + v0.z*wl[f0+2] + v0.w*wl[f0+3]
                  + v1.x*wl[256+f0] + v1.y*wl[256+f0+1] + v1.z*wl[256+f0+2] + v1.w*wl[256+f0+3];
        #pragma unroll
        for (int off = 32; off > 0; off >>= 1) dot += __shfl_xor(dot, off);
        if (lane == 0) left_att[i] = dot;
        if constexpr (WRITE_XBF) {
            ushort4 o0, o1;
            o0.x = f2bf(v0.x); o0.y = f2bf(v0.y); o0.z = f2bf(v0.z); o0.w = f2bf(v0.w);
            o1.x = f2bf(v1.x); o1.y = f2bf(v1.y); o1.z = f2bf(v1.z); o1.w = f2bf(v1.w);
            *reinterpret_cast<ushort4*>(xbf + (size_t)i * DIM + f0) = o0;
            *reinterpret_cast<ushort4*>(xbf + (size_t)i * DIM + 256 + f0) = o1;
        }
    }
    #pragma unroll
    for (int j = 0; j < 4; j++) {
        red[w * DIM + f0 + j]       = acc[j];
        red[w * DIM + 256 + f0 + j] = acc[4 + j];
    }
    __syncthreads();
    float s0 = red[t]       + red[DIM + t]       + red[2*DIM + t]       + red[3*DIM + t];
    float s1 = red[256 + t] + red[DIM + 256 + t] + red[2*DIM + 256 + t] + red[3*DIM + 256 + t];
    hcur[(size_t)b * DIM + t] = s0;
    hcur[(size_t)b * DIM + 256 + t] = s1;
    hcur_bf[(size_t)b * DIM + t] = f2bf(s0);
    hcur_bf[(size_t)b * DIM + 256 + t] = f2bf(s1);
}

// ---------------- fused attention: right-att dot + segment softmax + weighted sum ----------------
template<bool XBF>
__global__ __launch_bounds__(256) void k_att(const float* __restrict__ x,
        const unsigned short* __restrict__ xbf, const float* __restrict__ left,
        const int* __restrict__ starts, const float* __restrict__ hcur,
        const float* __restrict__ watr, unsigned short* __restrict__ swbf) {
    __shared__ float red[4 * DIM];
    __shared__ float rscal[8];
    int b = blockIdx.x, t = threadIdx.x;
    int w = t >> 6, lane = t & 63;

    float p = hcur[(size_t)b * DIM + t] * watr[t] + hcur[(size_t)b * DIM + 256 + t] * watr[256 + t];
    red[t] = p; __syncthreads();
    for (int off = 128; off > 0; off >>= 1) { if (t < off) red[t] += red[t + off]; __syncthreads(); }
    float ra = red[0];
    __syncthreads();

    int s = starts[b], e = starts[b + 1];
    float m = -1e30f;
    for (int i = s + t; i < e; i += 256) {
        float a = left[i] + ra; a = a >= 0.f ? a : 0.01f * a;
        m = fmaxf(m, a);
    }
    red[t] = m; __syncthreads();
    for (int off = 128; off > 0; off >>= 1) { if (t < off) red[t] = fmaxf(red[t], red[t + off]); __syncthreads(); }
    m = red[0];
    __syncthreads();

    float acc[8] = {0.f,0.f,0.f,0.f,0.f,0.f,0.f,0.f};
    float esum = 0.f;
    if constexpr (XBF) {
        int f0 = lane * 8;
        for (int i = s + w; i < e; i += 4) {
            float a = left[i] + ra; a = a >= 0.f ? a : 0.01f * a;
            float ev = __expf(a - m);
            esum += ev;
            short8 v = *reinterpret_cast<const short8*>(xbf + (size_t)i * DIM + f0);
            #pragma unroll
            for (int j = 0; j < 8; j++) acc[j] += ev * bf2f((unsigned short)v[j]);
        }
        #pragma unroll
        for (int j = 0; j < 8; j++) red[w * DIM + f0 + j] = acc[j];
    } else {
        int f0 = lane * 4;
        for (int i = s + w; i < e; i += 4) {
            float a = left[i] + ra; a = a >= 0.f ? a : 0.01f * a;
            float ev = __expf(a - m);
            esum += ev;
            float4 v0 = *reinterpret_cast<const float4*>(x + (size_t)i * DIM + f0);
            float4 v1 = *reinterpret_cast<const float4*>(x + (size_t)i * DIM + 256 + f0);
            acc[0] += ev * v0.x; acc[1] += ev * v0.y; acc[2] += ev * v0.z; acc[3] += ev * v0.w;
            acc[4] += ev * v1.x; acc[5] += ev * v1.y; acc[6] += ev * v1.z; acc[7] += ev * v1.w;
        }
        #pragma unroll
        for (int j = 0; j < 4; j++) {
            red[w * DIM + f0 + j]       = acc[j];
            red[w * DIM + 256 + f0 + j] = acc[4 + j];
        }
    }
    if (lane == 0) rscal[w] = esum;
    __syncthreads();
    float tot = rscal[0] + rscal[1] + rscal[2] + rscal[3];
    float inv = tot > 0.f ? 1.0f / tot : 0.0f;
    float s0 = (red[t]       + red[DIM + t]       + red[2*DIM + t]       + red[3*DIM + t])       * inv;
    float s1 = (red[256 + t] + red[DIM + 256 + t] + red[2*DIM + 256 + t] + red[3*DIM + 256 + t]) * inv;
    swbf[(size_t)b * DIM + t] = f2bf(s0);
    swbf[(size_t)b * DIM + 256 + t] = f2bf(s1);
}

// ---------------- bf16 MFMA GEMM, 2-phase global_load_lds pipeline ----------------
template<bool ELU_BF>
__global__ __launch_bounds__(256, 2) void k_gemm(const unsigned short* __restrict__ A0,
        const unsigned short* __restrict__ A1, const unsigned short* __restrict__ Wt0,
        const unsigned short* __restrict__ Wt1, float* __restrict__ Cf0,
        float* __restrict__ Cf1, unsigned short* __restrict__ Cbf, int Ncols) {
    __shared__ __align__(16) unsigned short lA[2][128 * 64];
    __shared__ __align__(16) unsigned short lW[2][128 * 64];
    const unsigned short* A  = (blockIdx.z == 0) ? A0  : A1;
    const unsigned short* Wt = (blockIdx.z == 0) ? Wt0 : Wt1;
    float* Cf = (blockIdx.z == 0) ? Cf0 : Cf1;

    int t = threadIdx.x;
    int w = t >> 6, lane = t & 63;
    int wr = w >> 1, wc = w & 1;
    int mbase = blockIdx.x * 128;
    int nbase = blockIdx.y * 128;
    int fr = lane & 15, hi = lane >> 4;
    int swz_r = (fr & 7) << 4;

    int rbase = t >> 3;
    int cole = ((((t & 7) * 16) ^ ((rbase & 7) << 4)) >> 1);
    int ldsoff = t * 16;

    floatx4 acc[4][4];
    #pragma unroll
    for (int m = 0; m < 4; m++)
        #pragma unroll
        for (int n = 0; n < 4; n++) {
            acc[m][n][0] = 0.f; acc[m][n][1] = 0.f; acc[m][n][2] = 0.f; acc[m][n][3] = 0.f;
        }

    const unsigned short* gA = A  + (size_t)(mbase + rbase) * DIM + cole;
    const unsigned short* gW = Wt + (size_t)(nbase + rbase) * DIM + cole;

    auto stage = [&](int kk, int buf) {
        #pragma unroll
        for (int c = 0; c < 4; ++c) {
            gload_lds16(gA + (size_t)(c * 32) * DIM + kk, (char*)&lA[buf][0] + c * 4096 + ldsoff);
            gload_lds16(gW + (size_t)(c * 32) * DIM + kk, (char*)&lW[buf][0] + c * 4096 + ldsoff);
        }
    };

    stage(0, 0);
    __syncthreads();
    int cur = 0;
    for (int it = 0; it < 8; ++it) {
        if (it < 7) stage((it + 1) * 64, cur ^ 1);
        #pragma unroll
        for (int ks = 0; ks < 2; ++ks) {
            short8 af[4], bf[4];
            int bc = (ks * 64 + hi * 16) ^ swz_r;
            #pragma unroll
            for (int m = 0; m < 4; ++m) {
                int row = wr * 64 + m * 16 + fr;
                af[m] = *reinterpret_cast<const short8*>(&lA[cur][(row * 128 + bc) >> 1]);
            }
            #pragma unroll
            for (int n = 0; n < 4; ++n) {
                int row = wc * 64 + n * 16 + fr;
                bf[n] = *reinterpret_cast<const short8*>(&lW[cur][(row * 128 + bc) >> 1]);
            }
            #pragma unroll
            for (int m = 0; m < 4; ++m)
                #pragma unroll
                for (int n = 0; n < 4; ++n)
                    acc[m][n] = __builtin_amdgcn_mfma_f32_16x16x32_bf16(af[m], bf[n], acc[m][n], 0, 0, 0);
        }
        if (it < 7) __syncthreads();
        cur ^= 1;
    }

    int rq = hi * 4;
    #pragma unroll
    for (int m = 0; m < 4; m++) {
        #pragma unroll
        for (int n = 0; n < 4; n++) {
            int col = nbase + wc * 64 + n * 16 + fr;
            #pragma unroll
            for (int r = 0; r < 4; r++) {
                int row = mbase + wr * 64 + m * 16 + rq + r;
                float v = acc[m][n][r];
                if constexpr (ELU_BF) {
                    v = v > 0.f ? v : (__expf(v) - 1.0f);
                    Cbf[(size_t)row * Ncols + col] = f2bf(v);
                } else {
                    Cf[(size_t)row * Ncols + col] = v;
                }
            }
        }
    }
}

// ---------------- GRU gates + silu ----------------
__global__ __launch_bounds__(256) void k_gate(const float* __restrict__ gi,
        const float* __restrict__ gh, const float* __restrict__ bih,
        const float* __restrict__ bhh, float* __restrict__ hcur,
        unsigned short* __restrict__ hcur_bf) {
    int idx = blockIdx.x * 256 + threadIdx.x;
    int b = idx >> 9, j = idx & 511;
    size_t gb = (size_t)b * HID3;
    float gir = gi[gb + j]        + bih[j];
    float giz = gi[gb + 512 + j]  + bih[512 + j];
    float gin = gi[gb + 1024 + j] + bih[1024 + j];
    float ghr = gh[gb + j]        + bhh[j];
    float ghz = gh[gb + 512 + j]  + bhh[512 + j];
    float ghn = gh[gb + 1024 + j] + bhh[1024 + j];
    float r = 1.0f / (1.0f + __expf(-(gir + ghr)));
    float z = 1.0f / (1.0f + __expf(-(giz + ghz)));
    float n = tanhf(gin + r * ghn);
    float h = hcur[(size_t)b * DIM + j];
    float nh = (1.0f - z) * n + z * h;
    float out = nh / (1.0f + __expf(-nh));
    hcur[(size_t)b * DIM + j] = out;
    hcur_bf[(size_t)b * DIM + j] = f2bf(out);
}

// ---------------- final linear ----------------
__global__ __launch_bounds__(128) void k_fin(const float* __restrict__ hcur,
        const float* __restrict__ Wlin, const float* __restrict__ blin,
        float* __restrict__ out) {
    __shared__ float rows[16 * DIM];
    int t = threadIdx.x;
    int b0 = blockIdx.x * 16;
    for (int i = t; i < 16 * DIM / 4; i += 128)
        reinterpret_cast<float4*>(rows)[i] = reinterpret_cast<const float4*>(hcur + (size_t)b0 * DIM)[i];
    __syncthreads();
    float acc[16];
    #pragma unroll
    for (int r = 0; r < 16; r++) acc[r] = 0.f;
    #pragma unroll 4
    for (int k = 0; k < DIM; k++) {
        float wv = Wlin[k * OUTD + t];
        #pragma unroll
        for (int r = 0; r < 16; r++) acc[r] += rows[r * DIM + k] * wv;
    }
    float bl = blin[t];
    #pragma unroll
    for (int r = 0; r < 16; r++) out[(size_t)(b0 + r) * OUTD + t] = acc[r] + bl;
}

extern "C" void kernel_launch(void* const* d_in, const int* in_sizes, int n_in,
                              void* d_out, int out_size, void* d_ws, size_t ws_size,
                              hipStream_t stream) {
    const float* x     = (const float*)d_in[0];
    const int*   seg   = (const int*)d_in[1];
    const float* watl  = (const float*)d_in[2];
    const float* watr  = (const float*)d_in[3];
    const float* Wnode = (const float*)d_in[4];
    const float* Wih   = (const float*)d_in[5];
    const float* Whh   = (const float*)d_in[6];
    const float* bih   = (const float*)d_in[7];
    const float* bhh   = (const float*)d_in[8];
    const float* Wlin  = (const float*)d_in[9];
    const float* blin  = (const float*)d_in[10];
    float* out = (float*)d_out;

    char* ws = (char*)d_ws;
    size_t off = 0;
    auto alloc = [&](size_t bytes) -> void* {
        void* p = ws + off;
        off += bytes;
        off = (off + 255) & ~(size_t)255;
        return p;
    };
    int*            starts  = (int*)            alloc((NGRAPH + 1) * sizeof(int));
    float*          left    = (float*)          alloc((size_t)N_NODES * sizeof(float));
    float*          hcur    = (float*)          alloc((size_t)NGRAPH * DIM * sizeof(float));
    unsigned short* hcurbf  = (unsigned short*) alloc((size_t)NGRAPH * DIM * 2);
    unsigned short* hgbf    = (unsigned short*) alloc((size_t)NGRAPH * DIM * 2);
    unsigned short* swbf    = (unsigned short*) alloc((size_t)NGRAPH * DIM * 2);
    float*          gi      = (float*)          alloc((size_t)NGRAPH * HID3 * sizeof(float));
    float*          gh      = (float*)          alloc((size_t)NGRAPH * HID3 * sizeof(float));
    unsigned short* WnT     = (unsigned short*) alloc((size_t)DIM * DIM * 2);
    unsigned short* Wihb    = (unsigned short*) alloc((size_t)HID3 * DIM * 2);
    unsigned short* Whhb    = (unsigned short*) alloc((size_t)HID3 * DIM * 2);
    unsigned short* xbf     = (unsigned short*)(ws + off);
    bool use_xbf = (off + (size_t)N_NODES * DIM * 2) <= ws_size;

    k_prep<<<6409, 256, 0, stream>>>(Wih, Whh, Wnode, seg, Wihb, Whhb, WnT, starts);

    if (use_xbf)
        k_init<true ><<<NGRAPH, 256, 0, stream>>>(x, starts, watl, left, hcur, hcurbf, xbf);
    else
        k_init<false><<<NGRAPH, 256, 0, stream>>>(x, starts, watl, left, hcur, hcurbf, nullptr);

    for (int ts = 0; ts < 2; ts++) {
        if (use_xbf)
            k_att<true ><<<NGRAPH, 256, 0, stream>>>(x, xbf, left, starts, hcur, watr, swbf);
        else
            k_att<false><<<NGRAPH, 256, 0, stream>>>(x, xbf, left, starts, hcur, watr, swbf);
        k_gemm<true ><<<dim3(NGRAPH / 128, DIM / 128, 1), 256, 0, stream>>>(
            swbf, nullptr, WnT, nullptr, nullptr, nullptr, hgbf, DIM);
        k_gemm<false><<<dim3(NGRAPH / 128, HID3 / 128, 2), 256, 0, stream>>>(
            hgbf, hcurbf, Wihb, Whhb, gi, gh, nullptr, HID3);
        k_gate<<<(NGRAPH * DIM) / 256, 256, 0, stream>>>(gi, gh, bih, bhh, hcur, hcurbf);
    }
    k_fin<<<NGRAPH / 16, 128, 0, stream>>>(hcur, Wlin, blin, out);
}